// Round 18
// baseline (239.487 us; speedup 1.0000x reference)
//
#include <hip/hip_runtime.h>
#include <hip/hip_bf16.h>

#define SEQ 2048
#define QSTR 4096
// (1/sqrt(128)) * log2(e)
#define CSCALE 0.1275174364688796f

typedef __attribute__((ext_vector_type(8)))  short short8;
typedef __attribute__((ext_vector_type(4)))  float f32x4;
typedef __attribute__((ext_vector_type(16))) float f32x16;

union PF8 { unsigned u[4]; short8 s; };

__device__ __forceinline__ unsigned short f2bf(float f) {
    union { __hip_bfloat16 b; unsigned short u; } cv;
    cv.b = __float2bfloat16(f);
    return cv.u;
}

__device__ __forceinline__ void gload16(const unsigned short* g, unsigned short* l) {
    __builtin_amdgcn_global_load_lds(
        (const __attribute__((address_space(1))) void*)g,
        (__attribute__((address_space(3))) void*)l, 16, 0, 0);
}

// ---- prepass: K -> bf16 [hk][kv][d] ----
__global__ void prep_k(const float* __restrict__ Kg, unsigned short* __restrict__ Kb) {
    int gi = blockIdx.x * 256 + threadIdx.x;
    int kv = gi >> 8;
    int rem = gi & 255;
    int hk = rem >> 5;
    int d4 = rem & 31;
    f32x4 k4 = *(const f32x4*)(Kg + ((size_t)kv * 8 + hk) * 128 + 4 * d4);
    ushort4 u = make_ushort4(f2bf(k4[0]), f2bf(k4[1]), f2bf(k4[2]), f2bf(k4[3]));
    *(ushort4*)(Kb + ((size_t)hk * SEQ + kv) * 128 + 4 * d4) = u;
}

// ---- prepass: V -> bf16 transposed [hk][d][kv] ----
__global__ void prep_v(const float* __restrict__ Vg, unsigned short* __restrict__ Vtb) {
    const int hk  = blockIdx.x >> 5;
    const int kvb = blockIdx.x & 31;
    __shared__ unsigned short T[128][72];
    const int t = threadIdx.x;
    #pragma unroll
    for (int i = 0; i < 8; ++i) {
        int idx = t + 256 * i;
        int r = idx >> 5, d4 = idx & 31;
        f32x4 v = *(const f32x4*)(Vg + ((size_t)(kvb * 64 + r) * 8 + hk) * 128 + 4 * d4);
        T[4 * d4 + 0][r] = f2bf(v[0]);
        T[4 * d4 + 1][r] = f2bf(v[1]);
        T[4 * d4 + 2][r] = f2bf(v[2]);
        T[4 * d4 + 3][r] = f2bf(v[3]);
    }
    __syncthreads();
    #pragma unroll
    for (int i = 0; i < 8; ++i) {
        int idx = t + 256 * i;
        int d = idx >> 4, c4 = idx & 15;
        ushort4 u = *(ushort4*)&T[d][4 * c4];
        *(ushort4*)(Vtb + ((size_t)hk * 128 + d) * SEQ + kvb * 64 + 4 * c4) = u;
    }
}

__launch_bounds__(512, 2)
__global__ void attn_fwd(const float* __restrict__ Qg,
                         const unsigned short* __restrict__ Kb,
                         const unsigned short* __restrict__ Vtb,
                         float* __restrict__ Og) {
    const int bid = blockIdx.x;            // 256 blocks, 1 per CU (LDS-capped)
    const int pr  = bid >> 5;              // 0..7 pair index
    const int h   = bid & 31;
    const int hk  = h >> 2;
    const int QBb = 15 - pr;               // big superblock (rows 128*QBb..+127)
    const int QBa = pr;                    // small superblock
    const int nsB = QBb + 1;               // 9..16; nsB + (QBa+1) == 17

    const int tid  = threadIdx.x;
    const int w    = tid >> 6;             // 0..7
    const int wq   = w & 3;                // q band
    const int wk   = w >> 2;               // kv half
    const int lane = tid & 63;
    const int q5   = lane & 31;
    const int t5   = lane >> 5;

    __shared__ __align__(16) unsigned char smem[150016];
    typedef unsigned short TileT[128][128];
    TileT* Ks = (TileT*)smem;                           // 2 x 32 KB, 4-bit XOR swizzle
    TileT* Vt = (TileT*)(smem + 65536);                 // 2 x 32 KB, packed-V layout
    float* mlm = (float*)(smem + 131072);               // [8][32]
    float* mll = (float*)(smem + 132096);               // [8][32]
    float (*Ot)[132] = (float(*)[132])(smem + 133120);  // [32][132] transpose scratch

    short8 qf[8], vregC[16];
    f32x16 oacc[4];
    float m, l;

    auto LOADQ = [&](int QB) __attribute__((always_inline)) {
        const float* qp = Qg + (size_t)(QB * 128 + 32 * wq + q5) * QSTR + h * 128 + 8 * t5;
        #pragma unroll
        for (int st = 0; st < 8; ++st) {
            f32x4 a = *(const f32x4*)(qp + 16 * st);
            f32x4 b = *(const f32x4*)(qp + 16 * st + 4);
            short8 f;
            f[0] = (short)f2bf(a[0] * CSCALE); f[1] = (short)f2bf(a[1] * CSCALE);
            f[2] = (short)f2bf(a[2] * CSCALE); f[3] = (short)f2bf(a[3] * CSCALE);
            f[4] = (short)f2bf(b[0] * CSCALE); f[5] = (short)f2bf(b[1] * CSCALE);
            f[6] = (short)f2bf(b[2] * CSCALE); f[7] = (short)f2bf(b[3] * CSCALE);
            qf[st] = f;
        }
    };

    auto ISSUE = [&](int kv0, int b) __attribute__((always_inline)) {
        #pragma unroll
        for (int p4 = 0; p4 < 4; ++p4) {
            int row = 16 * w + 4 * p4 + (lane >> 4);
            const unsigned short* g = Kb +
                ((size_t)hk * SEQ + kv0 + row) * 128 + 8 * ((lane & 15) ^ (row & 15));
            gload16(g, &Ks[b][16 * w + 4 * p4][0]);
        }
        #pragma unroll
        for (int p4 = 0; p4 < 4; ++p4) {
            int row16 = 16 * w + 4 * p4 + (lane >> 4);   // 0..127
            int hh = row16 >> 6, r = row16 & 63;
            int gg = lane & 15;
            int d  = 2 * r + (gg >> 3);
            int c  = (gg & 7) ^ (r & 7);
            const unsigned short* g = Vtb +
                ((size_t)hk * 128 + d) * SEQ + kv0 + 64 * hh + 8 * c;
            gload16(g, &Vt[b][16 * w + 4 * p4][0]);
        }
    };

    auto QKT = [&](int bb, f32x16 (&out)[2]) __attribute__((always_inline)) {
        __builtin_amdgcn_s_setprio(1);
        #pragma unroll
        for (int kvs = 0; kvs < 2; ++kvs) {
            f32x16 acc;
            #pragma unroll
            for (int r = 0; r < 16; ++r) acc[r] = 0.f;
            #pragma unroll
            for (int st = 0; st < 8; ++st) {
                short8 kf = *(const short8*)
                    &Ks[bb][64 * wk + 32 * kvs + q5][8 * ((2 * st + t5) ^ (q5 & 15))];
                acc = __builtin_amdgcn_mfma_f32_32x32x16_bf16(kf, qf[st], acc, 0, 0, 0);
            }
            out[kvs] = acc;
        }
        __builtin_amdgcn_s_setprio(0);
    };

    auto RFV = [&](int bb) __attribute__((always_inline)) {
        #pragma unroll
        for (int dt = 0; dt < 4; ++dt)
            #pragma unroll
            for (int ks = 0; ks < 4; ++ks) {
                const int gg = 8 * (q5 & 1) + ((2 * ks + t5) ^ ((q5 >> 1) & 7));
                vregC[4 * dt + ks] = *(const short8*)
                    &Vt[bb][64 * wk + 16 * dt + (q5 >> 1)][8 * gg];
            }
    };

    auto RESET = [&]() __attribute__((always_inline)) {
        #pragma unroll
        for (int dt = 0; dt < 4; ++dt)
            #pragma unroll
            for (int r = 0; r < 16; ++r) oacc[dt][r] = 0.f;
        m = -1e30f; l = 0.f;
    };

    auto EPI = [&](int QBp) __attribute__((always_inline)) {
        if (t5 == 0) mlm[w * 32 + q5] = m;
        asm volatile("s_waitcnt lgkmcnt(0)" ::: "memory");
        __builtin_amdgcn_sched_barrier(0);
        __builtin_amdgcn_s_barrier();
        const float mOth = mlm[(w ^ 4) * 32 + q5];
        const float M  = fmaxf(m, mOth);
        const float sc = exp2f(m - M);
        const float lp = l * sc;
        #pragma unroll
        for (int dt = 0; dt < 4; ++dt)
            #pragma unroll
            for (int r = 0; r < 16; ++r) oacc[dt][r] *= sc;
        if (t5 == 0) mll[w * 32 + q5] = lp;
        asm volatile("s_waitcnt lgkmcnt(0)" ::: "memory");
        __builtin_amdgcn_sched_barrier(0);
        __builtin_amdgcn_s_barrier();
        const float lOth = mll[(w ^ 4) * 32 + q5];

        #pragma unroll 1
        for (int tq = 0; tq < 4; ++tq) {
            if (w == tq + 4) {
                #pragma unroll
                for (int dt = 0; dt < 4; ++dt)
                    #pragma unroll
                    for (int b = 0; b < 4; ++b) {
                        f32x4 v;
                        v[0] = oacc[dt][4 * b + 0]; v[1] = oacc[dt][4 * b + 1];
                        v[2] = oacc[dt][4 * b + 2]; v[3] = oacc[dt][4 * b + 3];
                        *(f32x4*)&Ot[q5][32 * dt + 8 * b + 4 * t5] = v;
                    }
            }
            asm volatile("s_waitcnt lgkmcnt(0)" ::: "memory");
            __builtin_amdgcn_sched_barrier(0);
            __builtin_amdgcn_s_barrier();
            if (w == tq) {
                const float rl = 1.0f / (lp + lOth);
                #pragma unroll
                for (int dt = 0; dt < 4; ++dt)
                    #pragma unroll
                    for (int b = 0; b < 4; ++b) {
                        f32x4 o1 = *(const f32x4*)&Ot[q5][32 * dt + 8 * b + 4 * t5];
                        f32x4 oc;
                        oc[0] = (oacc[dt][4 * b + 0] + o1[0]) * rl;
                        oc[1] = (oacc[dt][4 * b + 1] + o1[1]) * rl;
                        oc[2] = (oacc[dt][4 * b + 2] + o1[2]) * rl;
                        oc[3] = (oacc[dt][4 * b + 3] + o1[3]) * rl;
                        *(f32x4*)&Ot[q5][32 * dt + 8 * b + 4 * t5] = oc;
                    }
            }
            asm volatile("s_waitcnt lgkmcnt(0)" ::: "memory");
            __builtin_amdgcn_sched_barrier(0);
            __builtin_amdgcn_s_barrier();
            {
                float* ob = Og + (size_t)(QBp * 128 + 32 * tq) * QSTR + h * 128;
                #pragma unroll
                for (int i = 0; i < 2; ++i) {
                    int u  = tid + 512 * i;
                    int r  = u >> 5;
                    int c4 = (u & 31) * 4;
                    f32x4 v = *(const f32x4*)&Ot[r][c4];
                    *(f32x4*)(ob + (size_t)r * QSTR + c4) = v;
                }
            }
            asm volatile("s_waitcnt lgkmcnt(0)" ::: "memory");
            __builtin_amdgcn_sched_barrier(0);
            __builtin_amdgcn_s_barrier();
        }
    };

    auto STEP = [&](f32x16 (&sacCur)[2], f32x16 (&sacNxt)[2], int s)
        __attribute__((always_inline)) {
        // single head barrier: own ds_reads drained + tile s+1 staged
        asm volatile("s_waitcnt vmcnt(0) lgkmcnt(0)" ::: "memory");
        __builtin_amdgcn_sched_barrier(0);
        __builtin_amdgcn_s_barrier();

        if (s == nsB - 1) LOADQ(QBa);       // QKT(nsB) below uses new qf
        if (s == nsB) { EPI(QBb); RESET(); }

        // stage tile s+2 into buf s&1 (dead: K(s),V(s) consumed at step s-1)
        if (s + 2 < 17) {
            const int x = s + 2;
            ISSUE((x < nsB) ? 128 * x : 128 * (x - nsB), s & 1);
        }

        // ---- QK(s+1) on MFMA pipe (overlaps softmax below) ----
        const int t1 = s + 1;
        bool act1 = false;
        if (t1 < 17) {
            const bool iB = t1 < nsB;
            const int kv0n = iB ? 128 * t1 : 128 * (t1 - nsB);
            const int q0n  = (iB ? QBb : QBa) * 128 + 32 * wq;
            act1 = (kv0n + 64 * wk) <= q0n + 31;
        }
        if (act1) QKT(t1 & 1, sacNxt);

        // ---- softmax + PV for tile s (V from vregC, prefetched step s-1) ----
        const bool iBt = s < nsB;
        const int kv0t = iBt ? 128 * s : 128 * (s - nsB);
        const int q0w  = (iBt ? QBb : QBa) * 128 + 32 * wq;
        const int kvb  = kv0t + 64 * wk;
        if (kvb <= q0w + 31) {
            if (kvb + 63 > q0w) {
                const int qrow = q0w + q5;
                #pragma unroll
                for (int kvs = 0; kvs < 2; ++kvs)
                    #pragma unroll
                    for (int r = 0; r < 16; ++r) {
                        int kv = kvb + 32 * kvs + (r & 3) + 8 * (r >> 2) + 4 * t5;
                        if (kv > qrow) sacCur[kvs][r] = -1e30f;
                    }
            }
            float t16[16], t8[8], t4[4], t2[2];
            #pragma unroll
            for (int i = 0; i < 16; ++i) t16[i] = fmaxf(sacCur[0][i], sacCur[1][i]);
            #pragma unroll
            for (int i = 0; i < 8; ++i) t8[i] = fmaxf(t16[i], t16[i + 8]);
            #pragma unroll
            for (int i = 0; i < 4; ++i) t4[i] = fmaxf(t8[i], t8[i + 4]);
            t2[0] = fmaxf(t4[0], t4[2]); t2[1] = fmaxf(t4[1], t4[3]);
            float mx = fmaxf(t2[0], t2[1]);
            mx = fmaxf(mx, __shfl_xor(mx, 32));

            const bool skip = __all(mx <= m + 11.0f);
            float fac = 1.0f;
            if (!skip) {
                float mn = fmaxf(m, mx);
                fac = exp2f(m - mn);
                m = mn;
            }
            float ps;
            {
                #pragma unroll
                for (int kvs = 0; kvs < 2; ++kvs)
                    #pragma unroll
                    for (int r = 0; r < 16; ++r)
                        sacCur[kvs][r] = exp2f(sacCur[kvs][r] - m);
                float s16[16], s8[8], s4[4], s2[2];
                #pragma unroll
                for (int i = 0; i < 16; ++i) s16[i] = sacCur[0][i] + sacCur[1][i];
                #pragma unroll
                for (int i = 0; i < 8; ++i) s8[i] = s16[i] + s16[i + 8];
                #pragma unroll
                for (int i = 0; i < 4; ++i) s4[i] = s8[i] + s8[i + 4];
                s2[0] = s4[0] + s4[2]; s2[1] = s4[1] + s4[3];
                ps = s2[0] + s2[1];
                ps += __shfl_xor(ps, 32);
            }
            if (!skip) {
                l = l * fac + ps;
                #pragma unroll
                for (int dt = 0; dt < 4; ++dt)
                    #pragma unroll
                    for (int r = 0; r < 16; ++r) oacc[dt][r] *= fac;
            } else {
                l += ps;
            }

            unsigned pkw[2][8];
            #pragma unroll
            for (int a = 0; a < 2; ++a)
                #pragma unroll
                for (int rp = 0; rp < 8; ++rp)
                    pkw[a][rp] = (unsigned)f2bf(sacCur[a][2 * rp]) |
                                 ((unsigned)f2bf(sacCur[a][2 * rp + 1]) << 16);

            unsigned rcv[2][4];
            #pragma unroll
            for (int a = 0; a < 2; ++a)
                #pragma unroll
                for (int i = 0; i < 4; ++i) {
                    const int loI = (i & 1) + 4 * (i >> 1);
                    const int hiI = loI + 2;
                    unsigned wsend = t5 ? pkw[a][loI] : pkw[a][hiI];
                    rcv[a][i] = (unsigned)__shfl_xor((int)wsend, 32);
                }

            PF8 pf[4];
            #pragma unroll
            for (int ks = 0; ks < 4; ++ks) {
                const int a = ks >> 1;
                #pragma unroll
                for (int j = 0; j < 4; ++j) {
                    const int ib = (j & 1) + 4 * (ks & 1);
                    const int ri = (j & 1) + 2 * (ks & 1);
                    const unsigned own_lo = pkw[a][ib];
                    const unsigned own_hi = pkw[a][ib + 2];
                    const unsigned par    = rcv[a][ri];
                    pf[ks].u[j] = (j < 2) ? (t5 ? par : own_lo)
                                          : (t5 ? own_hi : par);
                }
            }

            __builtin_amdgcn_s_setprio(1);
            #pragma unroll
            for (int dt = 0; dt < 4; ++dt)
                #pragma unroll
                for (int ks = 0; ks < 4; ++ks)
                    oacc[dt] = __builtin_amdgcn_mfma_f32_32x32x16_bf16(
                        vregC[4 * dt + ks], pf[ks].s, oacc[dt], 0, 0, 0);
            __builtin_amdgcn_s_setprio(0);
        }

        // ---- V frags for tile s+1 (buf (s+1)&1; drained at next head) ----
        if (act1) RFV(t1 & 1);
    };

    // ---- prologue ----
    LOADQ(QBb);
    #pragma unroll
    for (int st = 0; st < 8; ++st) asm volatile("" :: "v"(qf[st]));
    asm volatile("s_waitcnt vmcnt(0)" ::: "memory");
    RESET();
    ISSUE(0, 0);
    ISSUE(128, 1);
    asm volatile("s_waitcnt vmcnt(0)" ::: "memory");
    __builtin_amdgcn_s_barrier();

    f32x16 sacA[2], sacB[2];
    QKT(0, sacA);        // tile 0, phase B: all waves active (q0w >= 1024)
    RFV(0);

    #pragma unroll 1
    for (int s2 = 0; s2 < 8; ++s2) {
        STEP(sacA, sacB, 2 * s2);
        STEP(sacB, sacA, 2 * s2 + 1);
    }
    STEP(sacA, sacB, 16);

    EPI(QBa);
}

extern "C" void kernel_launch(void* const* d_in, const int* in_sizes, int n_in,
                              void* d_out, int out_size, void* d_ws, size_t ws_size,
                              hipStream_t stream) {
    const float* q = (const float*)d_in[0];
    const float* k = (const float*)d_in[1];
    const float* v = (const float*)d_in[2];
    float* out = (float*)d_out;
    unsigned short* Kb  = (unsigned short*)d_ws;                 // 4 MB
    unsigned short* Vtb = Kb + (size_t)8 * SEQ * 128;            // 4 MB
    prep_k<<<dim3(2048), 256, 0, stream>>>(k, Kb);
    prep_v<<<dim3(256), 256, 0, stream>>>(v, Vtb);
    attn_fwd<<<dim3(256), 512, 0, stream>>>(q, Kb, Vtb, out);
}

// Round 19
// 238.455 us; speedup vs baseline: 1.0043x; 1.0043x over previous
//
#include <hip/hip_runtime.h>
#include <hip/hip_bf16.h>

#define SEQ 2048
#define QSTR 4096
// (1/sqrt(128)) * log2(e)
#define CSCALE 0.1275174364688796f

typedef __attribute__((ext_vector_type(8)))  short short8;
typedef __attribute__((ext_vector_type(4)))  float f32x4;
typedef __attribute__((ext_vector_type(16))) float f32x16;

union PF8 { unsigned u[4]; short8 s; };

__device__ __forceinline__ unsigned short f2bf(float f) {
    union { __hip_bfloat16 b; unsigned short u; } cv;
    cv.b = __float2bfloat16(f);
    return cv.u;
}

__device__ __forceinline__ void gload16(const unsigned short* g, unsigned short* l) {
    __builtin_amdgcn_global_load_lds(
        (const __attribute__((address_space(1))) void*)g,
        (__attribute__((address_space(3))) void*)l, 16, 0, 0);
}

// ---- prepass: K -> bf16 [hk][kv][d] ----
__global__ void prep_k(const float* __restrict__ Kg, unsigned short* __restrict__ Kb) {
    int gi = blockIdx.x * 256 + threadIdx.x;
    int kv = gi >> 8;
    int rem = gi & 255;
    int hk = rem >> 5;
    int d4 = rem & 31;
    f32x4 k4 = *(const f32x4*)(Kg + ((size_t)kv * 8 + hk) * 128 + 4 * d4);
    ushort4 u = make_ushort4(f2bf(k4[0]), f2bf(k4[1]), f2bf(k4[2]), f2bf(k4[3]));
    *(ushort4*)(Kb + ((size_t)hk * SEQ + kv) * 128 + 4 * d4) = u;
}

// ---- prepass: V -> bf16 transposed [hk][d][kv] ----
__global__ void prep_v(const float* __restrict__ Vg, unsigned short* __restrict__ Vtb) {
    const int hk  = blockIdx.x >> 5;
    const int kvb = blockIdx.x & 31;
    __shared__ unsigned short T[128][72];
    const int t = threadIdx.x;
    #pragma unroll
    for (int i = 0; i < 8; ++i) {
        int idx = t + 256 * i;
        int r = idx >> 5, d4 = idx & 31;
        f32x4 v = *(const f32x4*)(Vg + ((size_t)(kvb * 64 + r) * 8 + hk) * 128 + 4 * d4);
        T[4 * d4 + 0][r] = f2bf(v[0]);
        T[4 * d4 + 1][r] = f2bf(v[1]);
        T[4 * d4 + 2][r] = f2bf(v[2]);
        T[4 * d4 + 3][r] = f2bf(v[3]);
    }
    __syncthreads();
    #pragma unroll
    for (int i = 0; i < 8; ++i) {
        int idx = t + 256 * i;
        int d = idx >> 4, c4 = idx & 15;
        ushort4 u = *(ushort4*)&T[d][4 * c4];
        *(ushort4*)(Vtb + ((size_t)hk * 128 + d) * SEQ + kvb * 64 + 4 * c4) = u;
    }
}

__launch_bounds__(512, 1)
__global__ void attn_fwd(const float* __restrict__ Qg,
                         const unsigned short* __restrict__ Kb,
                         const unsigned short* __restrict__ Vtb,
                         float* __restrict__ Og) {
    const int bid = blockIdx.x;            // 256 blocks, 1 per CU (LDS-capped)
    const int pr  = bid >> 5;              // 0..7 pair index
    const int h   = bid & 31;
    const int hk  = h >> 2;
    const int QBb = 15 - pr;               // big superblock (rows 128*QBb..+127)
    const int QBa = pr;                    // small superblock
    const int nsB = QBb + 1;               // 9..16; nsB + (QBa+1) == 17

    const int tid  = threadIdx.x;
    const int w    = tid >> 6;             // 0..7
    const int wq   = w & 3;                // q band
    const int wk   = w >> 2;               // kv half
    const int lane = tid & 63;
    const int q5   = lane & 31;
    const int t5   = lane >> 5;

    __shared__ __align__(16) unsigned char smem[150016];
    typedef unsigned short TileT[128][128];
    TileT* Ks = (TileT*)smem;                           // 2 x 32 KB, 4-bit XOR swizzle
    TileT* Vt = (TileT*)(smem + 65536);                 // 2 x 32 KB, packed-V layout
    float* mlm = (float*)(smem + 131072);               // [8][32]
    float* mll = (float*)(smem + 132096);               // [8][32]
    float (*Ot)[132] = (float(*)[132])(smem + 133120);  // [32][132] transpose scratch

    short8 qf[8], vregC[16];
    f32x16 oacc[4];
    float m, l;

    auto LOADQ = [&](int QB) __attribute__((always_inline)) {
        const float* qp = Qg + (size_t)(QB * 128 + 32 * wq + q5) * QSTR + h * 128 + 8 * t5;
        #pragma unroll
        for (int st = 0; st < 8; ++st) {
            f32x4 a = *(const f32x4*)(qp + 16 * st);
            f32x4 b = *(const f32x4*)(qp + 16 * st + 4);
            short8 f;
            f[0] = (short)f2bf(a[0] * CSCALE); f[1] = (short)f2bf(a[1] * CSCALE);
            f[2] = (short)f2bf(a[2] * CSCALE); f[3] = (short)f2bf(a[3] * CSCALE);
            f[4] = (short)f2bf(b[0] * CSCALE); f[5] = (short)f2bf(b[1] * CSCALE);
            f[6] = (short)f2bf(b[2] * CSCALE); f[7] = (short)f2bf(b[3] * CSCALE);
            qf[st] = f;
        }
    };

    auto ISSUE = [&](int kv0, int b) __attribute__((always_inline)) {
        #pragma unroll
        for (int p4 = 0; p4 < 4; ++p4) {
            int row = 16 * w + 4 * p4 + (lane >> 4);
            const unsigned short* g = Kb +
                ((size_t)hk * SEQ + kv0 + row) * 128 + 8 * ((lane & 15) ^ (row & 15));
            gload16(g, &Ks[b][16 * w + 4 * p4][0]);
        }
        #pragma unroll
        for (int p4 = 0; p4 < 4; ++p4) {
            int row16 = 16 * w + 4 * p4 + (lane >> 4);   // 0..127
            int hh = row16 >> 6, r = row16 & 63;
            int gg = lane & 15;
            int d  = 2 * r + (gg >> 3);
            int c  = (gg & 7) ^ (r & 7);
            const unsigned short* g = Vtb +
                ((size_t)hk * 128 + d) * SEQ + kv0 + 64 * hh + 8 * c;
            gload16(g, &Vt[b][16 * w + 4 * p4][0]);
        }
    };

    auto QKT = [&](int bb, f32x16 (&out)[2]) __attribute__((always_inline)) {
        __builtin_amdgcn_s_setprio(1);
        #pragma unroll
        for (int kvs = 0; kvs < 2; ++kvs) {
            f32x16 acc;
            #pragma unroll
            for (int r = 0; r < 16; ++r) acc[r] = 0.f;
            #pragma unroll
            for (int st = 0; st < 8; ++st) {
                short8 kf = *(const short8*)
                    &Ks[bb][64 * wk + 32 * kvs + q5][8 * ((2 * st + t5) ^ (q5 & 15))];
                acc = __builtin_amdgcn_mfma_f32_32x32x16_bf16(kf, qf[st], acc, 0, 0, 0);
            }
            out[kvs] = acc;
        }
        __builtin_amdgcn_s_setprio(0);
    };

    auto RFV = [&](int bb) __attribute__((always_inline)) {
        #pragma unroll
        for (int dt = 0; dt < 4; ++dt)
            #pragma unroll
            for (int ks = 0; ks < 4; ++ks) {
                const int gg = 8 * (q5 & 1) + ((2 * ks + t5) ^ ((q5 >> 1) & 7));
                vregC[4 * dt + ks] = *(const short8*)
                    &Vt[bb][64 * wk + 16 * dt + (q5 >> 1)][8 * gg];
            }
    };

    auto RESET = [&]() __attribute__((always_inline)) {
        #pragma unroll
        for (int dt = 0; dt < 4; ++dt)
            #pragma unroll
            for (int r = 0; r < 16; ++r) oacc[dt][r] = 0.f;
        m = -1e30f; l = 0.f;
    };

    auto EPI = [&](int QBp) __attribute__((always_inline)) {
        if (t5 == 0) mlm[w * 32 + q5] = m;
        asm volatile("s_waitcnt lgkmcnt(0)" ::: "memory");
        __builtin_amdgcn_sched_barrier(0);
        __builtin_amdgcn_s_barrier();
        const float mOth = mlm[(w ^ 4) * 32 + q5];
        const float M  = fmaxf(m, mOth);
        const float sc = exp2f(m - M);
        const float lp = l * sc;
        #pragma unroll
        for (int dt = 0; dt < 4; ++dt)
            #pragma unroll
            for (int r = 0; r < 16; ++r) oacc[dt][r] *= sc;
        if (t5 == 0) mll[w * 32 + q5] = lp;
        asm volatile("s_waitcnt lgkmcnt(0)" ::: "memory");
        __builtin_amdgcn_sched_barrier(0);
        __builtin_amdgcn_s_barrier();
        const float lOth = mll[(w ^ 4) * 32 + q5];

        #pragma unroll 1
        for (int tq = 0; tq < 4; ++tq) {
            if (w == tq + 4) {
                #pragma unroll
                for (int dt = 0; dt < 4; ++dt)
                    #pragma unroll
                    for (int b = 0; b < 4; ++b) {
                        f32x4 v;
                        v[0] = oacc[dt][4 * b + 0]; v[1] = oacc[dt][4 * b + 1];
                        v[2] = oacc[dt][4 * b + 2]; v[3] = oacc[dt][4 * b + 3];
                        *(f32x4*)&Ot[q5][32 * dt + 8 * b + 4 * t5] = v;
                    }
            }
            asm volatile("s_waitcnt lgkmcnt(0)" ::: "memory");
            __builtin_amdgcn_sched_barrier(0);
            __builtin_amdgcn_s_barrier();
            if (w == tq) {
                const float rl = 1.0f / (lp + lOth);
                #pragma unroll
                for (int dt = 0; dt < 4; ++dt)
                    #pragma unroll
                    for (int b = 0; b < 4; ++b) {
                        f32x4 o1 = *(const f32x4*)&Ot[q5][32 * dt + 8 * b + 4 * t5];
                        f32x4 oc;
                        oc[0] = (oacc[dt][4 * b + 0] + o1[0]) * rl;
                        oc[1] = (oacc[dt][4 * b + 1] + o1[1]) * rl;
                        oc[2] = (oacc[dt][4 * b + 2] + o1[2]) * rl;
                        oc[3] = (oacc[dt][4 * b + 3] + o1[3]) * rl;
                        *(f32x4*)&Ot[q5][32 * dt + 8 * b + 4 * t5] = oc;
                    }
            }
            asm volatile("s_waitcnt lgkmcnt(0)" ::: "memory");
            __builtin_amdgcn_sched_barrier(0);
            __builtin_amdgcn_s_barrier();
            {
                float* ob = Og + (size_t)(QBp * 128 + 32 * tq) * QSTR + h * 128;
                #pragma unroll
                for (int i = 0; i < 2; ++i) {
                    int u  = tid + 512 * i;
                    int r  = u >> 5;
                    int c4 = (u & 31) * 4;
                    f32x4 v = *(const f32x4*)&Ot[r][c4];
                    *(f32x4*)(ob + (size_t)r * QSTR + c4) = v;
                }
            }
            asm volatile("s_waitcnt lgkmcnt(0)" ::: "memory");
            __builtin_amdgcn_sched_barrier(0);
            __builtin_amdgcn_s_barrier();
        }
    };

    auto STEP = [&](f32x16 (&sacCur)[2], f32x16 (&sacNxt)[2], int s)
        __attribute__((always_inline)) {
        // single head barrier: own ds_reads drained + tile s+1 staged
        asm volatile("s_waitcnt vmcnt(0) lgkmcnt(0)" ::: "memory");
        __builtin_amdgcn_sched_barrier(0);
        __builtin_amdgcn_s_barrier();

        if (s == nsB - 1) LOADQ(QBa);       // QKT(nsB) below uses new qf
        if (s == nsB) { EPI(QBb); RESET(); }

        // stage tile s+2 into buf s&1 (dead: K(s),V(s) consumed at step s-1)
        if (s + 2 < 17) {
            const int x = s + 2;
            ISSUE((x < nsB) ? 128 * x : 128 * (x - nsB), s & 1);
        }

        // ---- QK(s+1) on MFMA pipe (overlaps softmax below) ----
        const int t1 = s + 1;
        bool act1 = false;
        if (t1 < 17) {
            const bool iB = t1 < nsB;
            const int kv0n = iB ? 128 * t1 : 128 * (t1 - nsB);
            const int q0n  = (iB ? QBb : QBa) * 128 + 32 * wq;
            act1 = (kv0n + 64 * wk) <= q0n + 31;
        }
        if (act1) QKT(t1 & 1, sacNxt);

        // ---- softmax + PV for tile s (V from vregC, prefetched step s-1) ----
        const bool iBt = s < nsB;
        const int kv0t = iBt ? 128 * s : 128 * (s - nsB);
        const int q0w  = (iBt ? QBb : QBa) * 128 + 32 * wq;
        const int kvb  = kv0t + 64 * wk;
        if (kvb <= q0w + 31) {
            if (kvb + 63 > q0w) {
                const int qrow = q0w + q5;
                #pragma unroll
                for (int kvs = 0; kvs < 2; ++kvs)
                    #pragma unroll
                    for (int r = 0; r < 16; ++r) {
                        int kv = kvb + 32 * kvs + (r & 3) + 8 * (r >> 2) + 4 * t5;
                        if (kv > qrow) sacCur[kvs][r] = -1e30f;
                    }
            }
            float t16[16], t8[8], t4[4], t2[2];
            #pragma unroll
            for (int i = 0; i < 16; ++i) t16[i] = fmaxf(sacCur[0][i], sacCur[1][i]);
            #pragma unroll
            for (int i = 0; i < 8; ++i) t8[i] = fmaxf(t16[i], t16[i + 8]);
            #pragma unroll
            for (int i = 0; i < 4; ++i) t4[i] = fmaxf(t8[i], t8[i + 4]);
            t2[0] = fmaxf(t4[0], t4[2]); t2[1] = fmaxf(t4[1], t4[3]);
            float mx = fmaxf(t2[0], t2[1]);
            mx = fmaxf(mx, __shfl_xor(mx, 32));

            const bool skip = __all(mx <= m + 11.0f);
            float fac = 1.0f;
            if (!skip) {
                float mn = fmaxf(m, mx);
                fac = exp2f(m - mn);
                m = mn;
            }
            float ps;
            {
                #pragma unroll
                for (int kvs = 0; kvs < 2; ++kvs)
                    #pragma unroll
                    for (int r = 0; r < 16; ++r)
                        sacCur[kvs][r] = exp2f(sacCur[kvs][r] - m);
                float s16[16], s8[8], s4[4], s2[2];
                #pragma unroll
                for (int i = 0; i < 16; ++i) s16[i] = sacCur[0][i] + sacCur[1][i];
                #pragma unroll
                for (int i = 0; i < 8; ++i) s8[i] = s16[i] + s16[i + 8];
                #pragma unroll
                for (int i = 0; i < 4; ++i) s4[i] = s8[i] + s8[i + 4];
                s2[0] = s4[0] + s4[2]; s2[1] = s4[1] + s4[3];
                ps = s2[0] + s2[1];
                ps += __shfl_xor(ps, 32);
            }
            if (!skip) {
                l = l * fac + ps;
                #pragma unroll
                for (int dt = 0; dt < 4; ++dt)
                    #pragma unroll
                    for (int r = 0; r < 16; ++r) oacc[dt][r] *= fac;
            } else {
                l += ps;
            }

            unsigned pkw[2][8];
            #pragma unroll
            for (int a = 0; a < 2; ++a)
                #pragma unroll
                for (int rp = 0; rp < 8; ++rp)
                    pkw[a][rp] = (unsigned)f2bf(sacCur[a][2 * rp]) |
                                 ((unsigned)f2bf(sacCur[a][2 * rp + 1]) << 16);

            unsigned rcv[2][4];
            #pragma unroll
            for (int a = 0; a < 2; ++a)
                #pragma unroll
                for (int i = 0; i < 4; ++i) {
                    const int loI = (i & 1) + 4 * (i >> 1);
                    const int hiI = loI + 2;
                    unsigned wsend = t5 ? pkw[a][loI] : pkw[a][hiI];
                    rcv[a][i] = (unsigned)__shfl_xor((int)wsend, 32);
                }

            PF8 pf[4];
            #pragma unroll
            for (int ks = 0; ks < 4; ++ks) {
                const int a = ks >> 1;
                #pragma unroll
                for (int j = 0; j < 4; ++j) {
                    const int ib = (j & 1) + 4 * (ks & 1);
                    const int ri = (j & 1) + 2 * (ks & 1);
                    const unsigned own_lo = pkw[a][ib];
                    const unsigned own_hi = pkw[a][ib + 2];
                    const unsigned par    = rcv[a][ri];
                    pf[ks].u[j] = (j < 2) ? (t5 ? par : own_lo)
                                          : (t5 ? own_hi : par);
                }
            }

            __builtin_amdgcn_s_setprio(1);
            #pragma unroll
            for (int dt = 0; dt < 4; ++dt)
                #pragma unroll
                for (int ks = 0; ks < 4; ++ks)
                    oacc[dt] = __builtin_amdgcn_mfma_f32_32x32x16_bf16(
                        vregC[4 * dt + ks], pf[ks].s, oacc[dt], 0, 0, 0);
            __builtin_amdgcn_s_setprio(0);
        }

        // ---- V frags for tile s+1 (buf (s+1)&1; drained at next head) ----
        if (act1) RFV(t1 & 1);
    };

    // ---- prologue ----
    LOADQ(QBb);
    #pragma unroll
    for (int st = 0; st < 8; ++st) asm volatile("" :: "v"(qf[st]));
    asm volatile("s_waitcnt vmcnt(0)" ::: "memory");
    RESET();
    ISSUE(0, 0);
    ISSUE(128, 1);
    asm volatile("s_waitcnt vmcnt(0)" ::: "memory");
    __builtin_amdgcn_s_barrier();

    f32x16 sacA[2], sacB[2];
    QKT(0, sacA);        // tile 0, phase B: all waves active (q0w >= 1024)
    RFV(0);

    #pragma unroll 1
    for (int s2 = 0; s2 < 8; ++s2) {
        STEP(sacA, sacB, 2 * s2);
        STEP(sacB, sacA, 2 * s2 + 1);
    }
    STEP(sacA, sacB, 16);

    EPI(QBa);
}

extern "C" void kernel_launch(void* const* d_in, const int* in_sizes, int n_in,
                              void* d_out, int out_size, void* d_ws, size_t ws_size,
                              hipStream_t stream) {
    const float* q = (const float*)d_in[0];
    const float* k = (const float*)d_in[1];
    const float* v = (const float*)d_in[2];
    float* out = (float*)d_out;
    unsigned short* Kb  = (unsigned short*)d_ws;                 // 4 MB
    unsigned short* Vtb = Kb + (size_t)8 * SEQ * 128;            // 4 MB
    prep_k<<<dim3(2048), 256, 0, stream>>>(k, Kb);
    prep_v<<<dim3(256), 256, 0, stream>>>(v, Vtb);
    attn_fwd<<<dim3(256), 512, 0, stream>>>(q, Kb, Vtb, out);
}

// Round 20
// 223.697 us; speedup vs baseline: 1.0706x; 1.0660x over previous
//
#include <hip/hip_runtime.h>
#include <hip/hip_bf16.h>

#define SEQ 2048
#define QSTR 4096
// (1/sqrt(128)) * log2(e)
#define CSCALE 0.1275174364688796f

typedef __attribute__((ext_vector_type(8)))  short short8;
typedef __attribute__((ext_vector_type(4)))  float f32x4;
typedef __attribute__((ext_vector_type(16))) float f32x16;

union PF8 { unsigned u[4]; short8 s; };

__device__ __forceinline__ unsigned short f2bf(float f) {
    union { __hip_bfloat16 b; unsigned short u; } cv;
    cv.b = __float2bfloat16(f);
    return cv.u;
}
__device__ __forceinline__ float bf2f(unsigned short u) {
    unsigned v = ((unsigned)u) << 16;
    return __builtin_bit_cast(float, v);
}

__device__ __forceinline__ void gload16(const unsigned short* g, unsigned short* l) {
    __builtin_amdgcn_global_load_lds(
        (const __attribute__((address_space(1))) void*)g,
        (__attribute__((address_space(3))) void*)l, 16, 0, 0);
}

// ---- prepass: K -> bf16 [hk][kv][d] ----
__global__ void prep_k(const float* __restrict__ Kg, unsigned short* __restrict__ Kb) {
    int gi = blockIdx.x * 256 + threadIdx.x;
    int kv = gi >> 8;
    int rem = gi & 255;
    int hk = rem >> 5;
    int d4 = rem & 31;
    f32x4 k4 = *(const f32x4*)(Kg + ((size_t)kv * 8 + hk) * 128 + 4 * d4);
    ushort4 u = make_ushort4(f2bf(k4[0]), f2bf(k4[1]), f2bf(k4[2]), f2bf(k4[3]));
    *(ushort4*)(Kb + ((size_t)hk * SEQ + kv) * 128 + 4 * d4) = u;
}

// ---- prepass: V -> bf16 transposed [hk][d][kv] ----
__global__ void prep_v(const float* __restrict__ Vg, unsigned short* __restrict__ Vtb) {
    const int hk  = blockIdx.x >> 5;
    const int kvb = blockIdx.x & 31;
    __shared__ unsigned short T[128][72];
    const int t = threadIdx.x;
    #pragma unroll
    for (int i = 0; i < 8; ++i) {
        int idx = t + 256 * i;
        int r = idx >> 5, d4 = idx & 31;
        f32x4 v = *(const f32x4*)(Vg + ((size_t)(kvb * 64 + r) * 8 + hk) * 128 + 4 * d4);
        T[4 * d4 + 0][r] = f2bf(v[0]);
        T[4 * d4 + 1][r] = f2bf(v[1]);
        T[4 * d4 + 2][r] = f2bf(v[2]);
        T[4 * d4 + 3][r] = f2bf(v[3]);
    }
    __syncthreads();
    #pragma unroll
    for (int i = 0; i < 8; ++i) {
        int idx = t + 256 * i;
        int d = idx >> 4, c4 = idx & 15;
        ushort4 u = *(ushort4*)&T[d][4 * c4];
        *(ushort4*)(Vtb + ((size_t)hk * 128 + d) * SEQ + kvb * 64 + 4 * c4) = u;
    }
}

__launch_bounds__(256, 3)
__global__ void attn_fwd(const float* __restrict__ Qg,
                         const unsigned short* __restrict__ Kb,
                         const unsigned short* __restrict__ Vtb,
                         float* __restrict__ Og) {
    const int bid = blockIdx.x;            // 512 blocks, all EXACTLY 33 steps
    const int p   = bid >> 5;              // 0..15
    const int h   = bid & 31;
    const int hk  = h >> 2;
    const int qbB = 31 - p;                // big 64-row q-block (phase B, first)
    const int qbA = p;                     // small (phase A)
    const int nsB = 32 - p;                // B steps; nsB + (p+1) == 33

    const int tid  = threadIdx.x;
    const int w    = tid >> 6;             // 0..3
    const int b    = w & 1;                // q band (32 rows)
    const int hf   = w >> 1;               // kv half (32 of 64)
    const int lane = tid & 63;
    const int q5   = lane & 31;
    const int t5   = lane >> 5;

    // single-buffered tiles: 41.5 KB total -> 3 blocks/CU = 12 waves/CU
    __shared__ unsigned short Ks[64][128];    // K row-major, granule ^= (row&15)
    __shared__ unsigned short Vp[64][128];    // packed V^T (R10 layout)
    __shared__ float mstat[2][4][32];
    __shared__ unsigned short Otb[32][136];   // bf16 partial-O exchange

    short8 qf[8];
    auto LOADQ = [&](int qb) __attribute__((always_inline)) {
        const float* qp = Qg + (size_t)(qb * 64 + 32 * b + q5) * QSTR + h * 128 + 8 * t5;
        #pragma unroll
        for (int st = 0; st < 8; ++st) {
            f32x4 a = *(const f32x4*)(qp + 16 * st);
            f32x4 c = *(const f32x4*)(qp + 16 * st + 4);
            short8 f;
            f[0] = (short)f2bf(a[0] * CSCALE); f[1] = (short)f2bf(a[1] * CSCALE);
            f[2] = (short)f2bf(a[2] * CSCALE); f[3] = (short)f2bf(a[3] * CSCALE);
            f[4] = (short)f2bf(c[0] * CSCALE); f[5] = (short)f2bf(c[1] * CSCALE);
            f[6] = (short)f2bf(c[2] * CSCALE); f[7] = (short)f2bf(c[3] * CSCALE);
            qf[st] = f;
        }
    };

    auto ISSUE = [&](int kv0) __attribute__((always_inline)) {
        #pragma unroll
        for (int p4 = 0; p4 < 4; ++p4) {
            int row = 16 * w + 4 * p4 + (lane >> 4);
            const unsigned short* g = Kb +
                ((size_t)hk * SEQ + kv0 + row) * 128 + 8 * ((lane & 15) ^ (row & 15));
            gload16(g, &Ks[16 * w + 4 * p4][0]);
        }
        #pragma unroll
        for (int p4 = 0; p4 < 4; ++p4) {
            int r  = 16 * w + 4 * p4 + (lane >> 4);
            int gg = lane & 15;
            int d  = 2 * r + (gg >> 3);
            int c  = (gg & 7) ^ (r & 7);
            const unsigned short* g = Vtb +
                ((size_t)hk * 128 + d) * SEQ + kv0 + 8 * c;
            gload16(g, &Vp[16 * w + 4 * p4][0]);
        }
    };

    f32x16 oacc[4];
    float m, l;
    auto RESET = [&]() __attribute__((always_inline)) {
        #pragma unroll
        for (int dt = 0; dt < 4; ++dt)
            #pragma unroll
            for (int r = 0; r < 16; ++r) oacc[dt][r] = 0.f;
        m = -1e30f; l = 0.f;
    };

    // phase-end: 2-way kv-half combine + coalesced store (Otb turns, bf16)
    auto EPI = [&](int qb) __attribute__((always_inline)) {
        if (t5 == 0) mstat[0][w][q5] = m;
        asm volatile("s_waitcnt lgkmcnt(0)" ::: "memory");
        __builtin_amdgcn_sched_barrier(0);
        __builtin_amdgcn_s_barrier();
        const float mo = mstat[0][w ^ 2][q5];
        const float M  = fmaxf(m, mo);
        const float sc = exp2f(m - M);
        #pragma unroll
        for (int dt = 0; dt < 4; ++dt)
            #pragma unroll
            for (int r = 0; r < 16; ++r) oacc[dt][r] *= sc;
        const float lp = l * sc;
        if (t5 == 0) mstat[1][w][q5] = lp;
        asm volatile("s_waitcnt lgkmcnt(0)" ::: "memory");
        __builtin_amdgcn_sched_barrier(0);
        __builtin_amdgcn_s_barrier();
        const float rl = 1.0f / (lp + mstat[1][w ^ 2][q5]);

        #pragma unroll 1
        for (int bb = 0; bb < 2; ++bb) {
            if (w == 2 + bb) {            // hf==1 wave of band bb: publish partial
                #pragma unroll
                for (int dt = 0; dt < 4; ++dt)
                    #pragma unroll
                    for (int ii = 0; ii < 4; ++ii) {
                        ushort4 u = make_ushort4(
                            f2bf(oacc[dt][4 * ii + 0]), f2bf(oacc[dt][4 * ii + 1]),
                            f2bf(oacc[dt][4 * ii + 2]), f2bf(oacc[dt][4 * ii + 3]));
                        *(ushort4*)&Otb[q5][32 * dt + 8 * ii + 4 * t5] = u;
                    }
            }
            asm volatile("s_waitcnt lgkmcnt(0)" ::: "memory");
            __builtin_amdgcn_sched_barrier(0);
            __builtin_amdgcn_s_barrier();
            if (w == bb) {                // hf==0 wave: combine + normalize
                #pragma unroll
                for (int dt = 0; dt < 4; ++dt)
                    #pragma unroll
                    for (int ii = 0; ii < 4; ++ii) {
                        ushort4 o1 = *(ushort4*)&Otb[q5][32 * dt + 8 * ii + 4 * t5];
                        ushort4 u = make_ushort4(
                            f2bf((oacc[dt][4 * ii + 0] + bf2f(o1.x)) * rl),
                            f2bf((oacc[dt][4 * ii + 1] + bf2f(o1.y)) * rl),
                            f2bf((oacc[dt][4 * ii + 2] + bf2f(o1.z)) * rl),
                            f2bf((oacc[dt][4 * ii + 3] + bf2f(o1.w)) * rl));
                        *(ushort4*)&Otb[q5][32 * dt + 8 * ii + 4 * t5] = u;
                    }
            }
            asm volatile("s_waitcnt lgkmcnt(0)" ::: "memory");
            __builtin_amdgcn_sched_barrier(0);
            __builtin_amdgcn_s_barrier();
            {   // all 256 threads: coalesced fp32 store of band bb rows
                const int r  = tid >> 3;
                const int c0 = 16 * (tid & 7);
                float* og = Og + (size_t)(qb * 64 + 32 * bb + r) * QSTR + h * 128 + c0;
                #pragma unroll
                for (int j = 0; j < 4; ++j) {
                    ushort4 u = *(ushort4*)&Otb[r][c0 + 4 * j];
                    f32x4 v;
                    v[0] = bf2f(u.x); v[1] = bf2f(u.y);
                    v[2] = bf2f(u.z); v[3] = bf2f(u.w);
                    *(f32x4*)(og + 4 * j) = v;
                }
            }
            asm volatile("s_waitcnt lgkmcnt(0)" ::: "memory");
            __builtin_amdgcn_sched_barrier(0);
            __builtin_amdgcn_s_barrier();
        }
    };

    LOADQ(qbB);
    #pragma unroll
    for (int st = 0; st < 8; ++st) asm volatile("" :: "v"(qf[st]));
    asm volatile("s_waitcnt vmcnt(0)" ::: "memory");
    RESET();

    for (int s = 0; s < 33; ++s) {
        if (s == nsB) {              // phase switch B -> A (LDS tiles idle here)
            LOADQ(qbA);
            EPI(qbB);
            RESET();
        }
        const bool isB = (s < nsB);
        const int kv0  = isB ? 64 * s : 64 * (s - nsB);
        const int qb   = isB ? qbB : qbA;
        const int q0w  = qb * 64 + 32 * b;

        // ---- stage this step's tile, then one barrier ----
        ISSUE(kv0);
        asm volatile("s_waitcnt vmcnt(0)" ::: "memory");
        __builtin_amdgcn_s_barrier();

        const int kvh = kv0 + 32 * hf;        // this wave's 32-kv chunk base
        if (kvh <= q0w + 31) {
            // ---- S^T = K Q^T : D[row=kv][col=q5] ----
            f32x16 sac;
            #pragma unroll
            for (int r = 0; r < 16; ++r) sac[r] = 0.f;
            __builtin_amdgcn_s_setprio(1);
            #pragma unroll
            for (int st = 0; st < 8; ++st) {
                short8 kf = *(const short8*)
                    &Ks[32 * hf + q5][8 * ((2 * st + t5) ^ (q5 & 15))];
                sac = __builtin_amdgcn_mfma_f32_32x32x16_bf16(kf, qf[st], sac, 0, 0, 0);
            }
            __builtin_amdgcn_s_setprio(0);

            // ---- mask (diagonal only) ----
            if (kvh + 31 > q0w) {
                const int qrow = q0w + q5;
                #pragma unroll
                for (int r = 0; r < 16; ++r) {
                    int kv = kvh + (r & 3) + 8 * (r >> 2) + 4 * t5;
                    if (kv > qrow) sac[r] = -1e30f;
                }
            }

            // ---- row max: depth-4 tree + one cross-lane ----
            float m8[8], m4[4], m2[2];
            #pragma unroll
            for (int i = 0; i < 8; ++i) m8[i] = fmaxf(sac[i], sac[i + 8]);
            #pragma unroll
            for (int i = 0; i < 4; ++i) m4[i] = fmaxf(m8[i], m8[i + 4]);
            m2[0] = fmaxf(m4[0], m4[2]); m2[1] = fmaxf(m4[1], m4[3]);
            float mx = fmaxf(m2[0], m2[1]);
            mx = fmaxf(mx, __shfl_xor(mx, 32));

            // ---- defer-max (T13) ----
            const bool skip = __all(mx <= m + 11.0f);
            float fac = 1.0f;
            if (!skip) {
                float mn = fmaxf(m, mx);
                fac = exp2f(m - mn);
                m = mn;
            }

            // ---- P = 2^(S-m); depth-4 tree sum ----
            #pragma unroll
            for (int r = 0; r < 16; ++r) sac[r] = exp2f(sac[r] - m);
            float s8[8], s4[4], s2[2];
            #pragma unroll
            for (int i = 0; i < 8; ++i) s8[i] = sac[i] + sac[i + 8];
            #pragma unroll
            for (int i = 0; i < 4; ++i) s4[i] = s8[i] + s8[i + 4];
            s2[0] = s4[0] + s4[2]; s2[1] = s4[1] + s4[3];
            float ps = s2[0] + s2[1];
            ps += __shfl_xor(ps, 32);
            if (!skip) {
                l = l * fac + ps;
                #pragma unroll
                for (int dt = 0; dt < 4; ++dt)
                    #pragma unroll
                    for (int r = 0; r < 16; ++r) oacc[dt][r] *= fac;
            } else {
                l += ps;
            }

            // ---- pack P pairs to bf16x2 ----
            unsigned pkw[8];
            #pragma unroll
            for (int rp = 0; rp < 8; ++rp)
                pkw[rp] = (unsigned)f2bf(sac[2 * rp]) |
                          ((unsigned)f2bf(sac[2 * rp + 1]) << 16);

            // ---- redistribute: 4 shfl via t5-preselected send (R17 halving) ----
            unsigned rcv[4];
            #pragma unroll
            for (int i = 0; i < 4; ++i) {
                const int loI = (i & 1) + 4 * (i >> 1);       // {0,1,4,5}
                const int hiI = loI + 2;                      // {2,3,6,7}
                unsigned wsend = t5 ? pkw[loI] : pkw[hiI];
                rcv[i] = (unsigned)__shfl_xor((int)wsend, 32);
            }

            PF8 pf[2];
            #pragma unroll
            for (int ks = 0; ks < 2; ++ks) {
                #pragma unroll
                for (int j = 0; j < 4; ++j) {
                    const int ib = (j & 1) + 4 * ks;
                    const int ri = (j & 1) + 2 * ks;
                    const unsigned own_lo = pkw[ib];
                    const unsigned own_hi = pkw[ib + 2];
                    const unsigned par    = rcv[ri];
                    pf[ks].u[j] = (j < 2) ? (t5 ? par : own_lo)
                                          : (t5 ? own_hi : par);
                }
            }

            // ---- O^T += V^T P (packed-V read, 2-way max banks) ----
            __builtin_amdgcn_s_setprio(1);
            #pragma unroll
            for (int dt = 0; dt < 4; ++dt) {
                #pragma unroll
                for (int ks = 0; ks < 2; ++ks) {
                    const int gg = 8 * (q5 & 1) +
                        ((4 * hf + 2 * ks + t5) ^ ((q5 >> 1) & 7));
                    short8 vf = *(const short8*)
                        &Vp[16 * dt + (q5 >> 1)][8 * gg];
                    oacc[dt] = __builtin_amdgcn_mfma_f32_32x32x16_bf16(vf, pf[ks].s, oacc[dt], 0, 0, 0);
                }
            }
            __builtin_amdgcn_s_setprio(0);
        }

        asm volatile("" ::: "memory");
        __builtin_amdgcn_s_barrier();   // all reads done before next ISSUE
    }

    EPI(qbA);
}

extern "C" void kernel_launch(void* const* d_in, const int* in_sizes, int n_in,
                              void* d_out, int out_size, void* d_ws, size_t ws_size,
                              hipStream_t stream) {
    const float* q = (const float*)d_in[0];
    const float* k = (const float*)d_in[1];
    const float* v = (const float*)d_in[2];
    float* out = (float*)d_out;
    unsigned short* Kb  = (unsigned short*)d_ws;                 // 4 MB
    unsigned short* Vtb = Kb + (size_t)8 * SEQ * 128;            // 4 MB
    prep_k<<<dim3(2048), 256, 0, stream>>>(k, Kb);
    prep_v<<<dim3(256), 256, 0, stream>>>(v, Vtb);
    attn_fwd<<<dim3(512), 256, 0, stream>>>(q, Kb, Vtb, out);
}

// Round 21
// 87.307 us; speedup vs baseline: 2.7430x; 2.5622x over previous
//
#include <hip/hip_runtime.h>
#include <hip/hip_bf16.h>

#define SEQ 2048
#define QSTR 4096
// (1/sqrt(128)) * log2(e)
#define CSCALE 0.1275174364688796f

typedef __attribute__((ext_vector_type(8)))  short short8;
typedef __attribute__((ext_vector_type(4)))  float f32x4;
typedef __attribute__((ext_vector_type(16))) float f32x16;

union PF8 { unsigned u[4]; short8 s; };

__device__ __forceinline__ unsigned short f2bf(float f) {
    union { __hip_bfloat16 b; unsigned short u; } cv;
    cv.b = __float2bfloat16(f);
    return cv.u;
}

__device__ __forceinline__ void gload16(const unsigned short* g, unsigned short* l) {
    __builtin_amdgcn_global_load_lds(
        (const __attribute__((address_space(1))) void*)g,
        (__attribute__((address_space(3))) void*)l, 16, 0, 0);
}

// ---- prepass: K -> bf16 [hk][kv][d] ----
__global__ void prep_k(const float* __restrict__ Kg, unsigned short* __restrict__ Kb) {
    int gi = blockIdx.x * 256 + threadIdx.x;
    int kv = gi >> 8;
    int rem = gi & 255;
    int hk = rem >> 5;
    int d4 = rem & 31;
    f32x4 k4 = *(const f32x4*)(Kg + ((size_t)kv * 8 + hk) * 128 + 4 * d4);
    ushort4 u = make_ushort4(f2bf(k4[0]), f2bf(k4[1]), f2bf(k4[2]), f2bf(k4[3]));
    *(ushort4*)(Kb + ((size_t)hk * SEQ + kv) * 128 + 4 * d4) = u;
}

// ---- prepass: V -> bf16 transposed [hk][d][kv] ----
__global__ void prep_v(const float* __restrict__ Vg, unsigned short* __restrict__ Vtb) {
    const int hk  = blockIdx.x >> 5;
    const int kvb = blockIdx.x & 31;
    __shared__ unsigned short T[128][72];
    const int t = threadIdx.x;
    #pragma unroll
    for (int i = 0; i < 8; ++i) {
        int idx = t + 256 * i;
        int r = idx >> 5, d4 = idx & 31;
        f32x4 v = *(const f32x4*)(Vg + ((size_t)(kvb * 64 + r) * 8 + hk) * 128 + 4 * d4);
        T[4 * d4 + 0][r] = f2bf(v[0]);
        T[4 * d4 + 1][r] = f2bf(v[1]);
        T[4 * d4 + 2][r] = f2bf(v[2]);
        T[4 * d4 + 3][r] = f2bf(v[3]);
    }
    __syncthreads();
    #pragma unroll
    for (int i = 0; i < 8; ++i) {
        int idx = t + 256 * i;
        int d = idx >> 4, c4 = idx & 15;
        ushort4 u = *(ushort4*)&T[d][4 * c4];
        *(ushort4*)(Vtb + ((size_t)hk * 128 + d) * SEQ + kvb * 64 + 4 * c4) = u;
    }
}

__launch_bounds__(512, 2)
__global__ void attn_fwd(const float* __restrict__ Qg,
                         const unsigned short* __restrict__ Kb,
                         const unsigned short* __restrict__ Vtb,
                         float* __restrict__ Og) {
    const int bid = blockIdx.x;            // 256 blocks, 1 per CU (LDS-capped)
    // XCD-aware decode: bid%8 == hk  ->  each XCD's L2 serves ONE kv-head (1 MB)
    const int hk  = bid & 7;
    const int idx = bid >> 3;              // 0..31
    const int pr  = idx >> 2;              // 0..7 pair index
    const int h   = 4 * hk + (idx & 3);
    const int QBb = 15 - pr;               // big superblock (rows 128*QBb..+127)
    const int QBa = pr;                    // small superblock
    const int nsB = QBb + 1;               // 9..16; nsB + (QBa+1) == 17

    const int tid  = threadIdx.x;
    const int w    = tid >> 6;             // 0..7
    const int wq   = w & 3;                // q band
    const int wk   = w >> 2;               // kv half
    const int lane = tid & 63;
    const int q5   = lane & 31;
    const int t5   = lane >> 5;

    __shared__ __align__(16) unsigned char smem[150016];
    typedef unsigned short TileT[128][128];
    TileT* Ks = (TileT*)smem;                           // 2 x 32 KB, 4-bit XOR swizzle
    TileT* Vt = (TileT*)(smem + 65536);                 // 2 x 32 KB, packed-V layout
    float* mlm = (float*)(smem + 131072);               // [8][32]
    float* mll = (float*)(smem + 132096);               // [8][32]
    float (*Ot)[132] = (float(*)[132])(smem + 133120);  // [32][132] transpose scratch

    // ---- Q fragments (working set; reloaded at phase switch) ----
    short8 qf[8];
    auto LOADQ = [&](int QB) __attribute__((always_inline)) {
        const float* qp = Qg + (size_t)(QB * 128 + 32 * wq + q5) * QSTR + h * 128 + 8 * t5;
        #pragma unroll
        for (int st = 0; st < 8; ++st) {
            f32x4 a = *(const f32x4*)(qp + 16 * st);
            f32x4 b = *(const f32x4*)(qp + 16 * st + 4);
            short8 f;
            f[0] = (short)f2bf(a[0] * CSCALE); f[1] = (short)f2bf(a[1] * CSCALE);
            f[2] = (short)f2bf(a[2] * CSCALE); f[3] = (short)f2bf(a[3] * CSCALE);
            f[4] = (short)f2bf(b[0] * CSCALE); f[5] = (short)f2bf(b[1] * CSCALE);
            f[6] = (short)f2bf(b[2] * CSCALE); f[7] = (short)f2bf(b[3] * CSCALE);
            qf[st] = f;
        }
    };

    auto ISSUE = [&](int kv0, int b) __attribute__((always_inline)) {
        // K: linear LDS dest, 4-bit inverse-swizzled source (2-way max on read)
        #pragma unroll
        for (int p4 = 0; p4 < 4; ++p4) {
            int row = 16 * w + 4 * p4 + (lane >> 4);
            const unsigned short* g = Kb +
                ((size_t)hk * SEQ + kv0 + row) * 128 + 8 * ((lane & 15) ^ (row & 15));
            gload16(g, &Ks[b][16 * w + 4 * p4][0]);
        }
        // V packed: LDS row16 = 64*hh + r holds d = 2r+(gg>>3), kv-granule (gg&7)^(r&7)
        #pragma unroll
        for (int p4 = 0; p4 < 4; ++p4) {
            int row16 = 16 * w + 4 * p4 + (lane >> 4);   // 0..127
            int hh = row16 >> 6, r = row16 & 63;
            int gg = lane & 15;
            int d  = 2 * r + (gg >> 3);
            int c  = (gg & 7) ^ (r & 7);
            const unsigned short* g = Vtb +
                ((size_t)hk * 128 + d) * SEQ + kv0 + 64 * hh + 8 * c;
            gload16(g, &Vt[b][16 * w + 4 * p4][0]);
        }
    };

    f32x16 oacc[4];
    float m, l;
    auto RESET = [&]() __attribute__((always_inline)) {
        #pragma unroll
        for (int dt = 0; dt < 4; ++dt)
            #pragma unroll
            for (int r = 0; r < 16; ++r) oacc[dt][r] = 0.f;
        m = -1e30f; l = 0.f;
    };

    // phase-end: combine kv-half partials (flash-decoding algebra) + store
    auto EPI = [&](int QBp) __attribute__((always_inline)) {
        if (t5 == 0) mlm[w * 32 + q5] = m;
        asm volatile("s_waitcnt lgkmcnt(0)" ::: "memory");
        __builtin_amdgcn_sched_barrier(0);
        __builtin_amdgcn_s_barrier();
        const float mOth = mlm[(w ^ 4) * 32 + q5];
        const float M  = fmaxf(m, mOth);
        const float sc = exp2f(m - M);
        const float lp = l * sc;
        #pragma unroll
        for (int dt = 0; dt < 4; ++dt)
            #pragma unroll
            for (int r = 0; r < 16; ++r) oacc[dt][r] *= sc;
        if (t5 == 0) mll[w * 32 + q5] = lp;
        asm volatile("s_waitcnt lgkmcnt(0)" ::: "memory");
        __builtin_amdgcn_sched_barrier(0);
        __builtin_amdgcn_s_barrier();
        const float lOth = mll[(w ^ 4) * 32 + q5];

        #pragma unroll 1
        for (int tq = 0; tq < 4; ++tq) {
            if (w == tq + 4) {            // kv-half-1 wave of band tq: publish partial
                #pragma unroll
                for (int dt = 0; dt < 4; ++dt)
                    #pragma unroll
                    for (int b = 0; b < 4; ++b) {
                        f32x4 v;
                        v[0] = oacc[dt][4 * b + 0]; v[1] = oacc[dt][4 * b + 1];
                        v[2] = oacc[dt][4 * b + 2]; v[3] = oacc[dt][4 * b + 3];
                        *(f32x4*)&Ot[q5][32 * dt + 8 * b + 4 * t5] = v;
                    }
            }
            asm volatile("s_waitcnt lgkmcnt(0)" ::: "memory");
            __builtin_amdgcn_sched_barrier(0);
            __builtin_amdgcn_s_barrier();
            if (w == tq) {                // kv-half-0 wave: combine + normalize
                const float rl = 1.0f / (lp + lOth);
                #pragma unroll
                for (int dt = 0; dt < 4; ++dt)
                    #pragma unroll
                    for (int b = 0; b < 4; ++b) {
                        f32x4 o1 = *(const f32x4*)&Ot[q5][32 * dt + 8 * b + 4 * t5];
                        f32x4 oc;
                        oc[0] = (oacc[dt][4 * b + 0] + o1[0]) * rl;
                        oc[1] = (oacc[dt][4 * b + 1] + o1[1]) * rl;
                        oc[2] = (oacc[dt][4 * b + 2] + o1[2]) * rl;
                        oc[3] = (oacc[dt][4 * b + 3] + o1[3]) * rl;
                        *(f32x4*)&Ot[q5][32 * dt + 8 * b + 4 * t5] = oc;
                    }
            }
            asm volatile("s_waitcnt lgkmcnt(0)" ::: "memory");
            __builtin_amdgcn_sched_barrier(0);
            __builtin_amdgcn_s_barrier();
            {   // all 512 threads: coalesced store of rows 128*QBp + 32*tq ..+31
                float* ob = Og + (size_t)(QBp * 128 + 32 * tq) * QSTR + h * 128;
                #pragma unroll
                for (int i = 0; i < 2; ++i) {
                    int u  = tid + 512 * i;        // 0..1023
                    int r  = u >> 5;
                    int c4 = (u & 31) * 4;
                    f32x4 v = *(const f32x4*)&Ot[r][c4];
                    *(f32x4*)(ob + (size_t)r * QSTR + c4) = v;
                }
            }
            asm volatile("s_waitcnt lgkmcnt(0)" ::: "memory");
            __builtin_amdgcn_sched_barrier(0);
            __builtin_amdgcn_s_barrier();
        }
    };

    LOADQ(QBb);
    #pragma unroll
    for (int st = 0; st < 8; ++st) asm volatile("" :: "v"(qf[st]));
    asm volatile("s_waitcnt vmcnt(0)" ::: "memory");
    RESET();

    ISSUE(0, 0);
    ISSUE(128, 1);    // nsB >= 9, so step 1 is always a B tile

    for (int s = 0; s < 17; ++s) {
        if (s == nsB) {               // phase switch: B done -> A
            LOADQ(QBa);               // flies during EPI
            EPI(QBb);
            RESET();
        }
        const bool isB = (s < nsB);
        const int kv0   = isB ? 128 * s : 128 * (s - nsB);
        const int q0blk = isB ? 128 * QBb : 128 * QBa;
        const int buf = s & 1;

        if (s + 1 < 17) asm volatile("s_waitcnt vmcnt(8)" ::: "memory");
        else            asm volatile("s_waitcnt vmcnt(0)" ::: "memory");
        __builtin_amdgcn_s_barrier();

        const int q0w = q0blk + 32 * wq;
        const int kvb = kv0 + 64 * wk;         // this wave's kv-half base
        if (kvb <= q0w + 31) {
            // ---- S^T = K Q^T on own kv-half ----
            f32x16 sac[2];
            __builtin_amdgcn_s_setprio(1);
            #pragma unroll
            for (int kvs = 0; kvs < 2; ++kvs) {
                f32x16 acc;
                #pragma unroll
                for (int r = 0; r < 16; ++r) acc[r] = 0.f;
                #pragma unroll
                for (int st = 0; st < 8; ++st) {
                    short8 kf = *(const short8*)
                        &Ks[buf][64 * wk + 32 * kvs + q5][8 * ((2 * st + t5) ^ (q5 & 15))];
                    acc = __builtin_amdgcn_mfma_f32_32x32x16_bf16(kf, qf[st], acc, 0, 0, 0);
                }
                sac[kvs] = acc;
            }
            __builtin_amdgcn_s_setprio(0);

            // ---- mask (diagonal only) ----
            if (kvb + 63 > q0w) {
                const int qrow = q0w + q5;
                #pragma unroll
                for (int kvs = 0; kvs < 2; ++kvs)
                    #pragma unroll
                    for (int r = 0; r < 16; ++r) {
                        int kv = kvb + 32 * kvs + (r & 3) + 8 * (r >> 2) + 4 * t5;
                        if (kv > qrow) sac[kvs][r] = -1e30f;
                    }
            }

            // ---- row max: depth-5 tree + one cross-lane ----
            float t16[16], t8[8], t4[4], t2[2];
            #pragma unroll
            for (int i = 0; i < 16; ++i) t16[i] = fmaxf(sac[0][i], sac[1][i]);
            #pragma unroll
            for (int i = 0; i < 8; ++i) t8[i] = fmaxf(t16[i], t16[i + 8]);
            #pragma unroll
            for (int i = 0; i < 4; ++i) t4[i] = fmaxf(t8[i], t8[i + 4]);
            t2[0] = fmaxf(t4[0], t4[2]); t2[1] = fmaxf(t4[1], t4[3]);
            float mx = fmaxf(t2[0], t2[1]);
            mx = fmaxf(mx, __shfl_xor(mx, 32));

            // ---- defer-max (T13) ----
            const bool skip = __all(mx <= m + 11.0f);
            float fac = 1.0f;
            if (!skip) {
                float mn = fmaxf(m, mx);
                fac = exp2f(m - mn);
                m = mn;
            }

            // ---- P = 2^(S-m); depth-5 tree sum ----
            float ps;
            {
                #pragma unroll
                for (int kvs = 0; kvs < 2; ++kvs)
                    #pragma unroll
                    for (int r = 0; r < 16; ++r)
                        sac[kvs][r] = exp2f(sac[kvs][r] - m);
                float s16[16], s8[8], s4[4], s2[2];
                #pragma unroll
                for (int i = 0; i < 16; ++i) s16[i] = sac[0][i] + sac[1][i];
                #pragma unroll
                for (int i = 0; i < 8; ++i) s8[i] = s16[i] + s16[i + 8];
                #pragma unroll
                for (int i = 0; i < 4; ++i) s4[i] = s8[i] + s8[i + 4];
                s2[0] = s4[0] + s4[2]; s2[1] = s4[1] + s4[3];
                ps = s2[0] + s2[1];
                ps += __shfl_xor(ps, 32);
            }
            if (!skip) {
                l = l * fac + ps;
                #pragma unroll
                for (int dt = 0; dt < 4; ++dt)
                    #pragma unroll
                    for (int r = 0; r < 16; ++r) oacc[dt][r] *= fac;
            } else {
                l += ps;
            }

            // ---- pack P pairs to bf16x2 ----
            unsigned pkw[2][8];
            #pragma unroll
            for (int a = 0; a < 2; ++a)
                #pragma unroll
                for (int rp = 0; rp < 8; ++rp)
                    pkw[a][rp] = (unsigned)f2bf(sac[a][2 * rp]) |
                                 ((unsigned)f2bf(sac[a][2 * rp + 1]) << 16);

            // ---- redistribute: 8 shfl via t5-preselected send ----
            unsigned rcv[2][4];
            #pragma unroll
            for (int a = 0; a < 2; ++a)
                #pragma unroll
                for (int i = 0; i < 4; ++i) {
                    const int loI = (i & 1) + 4 * (i >> 1);       // {0,1,4,5}
                    const int hiI = loI + 2;                      // {2,3,6,7}
                    unsigned wsend = t5 ? pkw[a][loI] : pkw[a][hiI];
                    rcv[a][i] = (unsigned)__shfl_xor((int)wsend, 32);
                }

            PF8 pf[4];
            #pragma unroll
            for (int ks = 0; ks < 4; ++ks) {
                const int a = ks >> 1;
                #pragma unroll
                for (int j = 0; j < 4; ++j) {
                    const int ib = (j & 1) + 4 * (ks & 1);
                    const int ri = (j & 1) + 2 * (ks & 1);        // recv index
                    const unsigned own_lo = pkw[a][ib];
                    const unsigned own_hi = pkw[a][ib + 2];
                    const unsigned par    = rcv[a][ri];
                    pf[ks].u[j] = (j < 2) ? (t5 ? par : own_lo)
                                          : (t5 ? own_hi : par);
                }
            }

            // ---- O^T += V^T P (packed-V read: 2-way max banks) ----
            __builtin_amdgcn_s_setprio(1);
            #pragma unroll
            for (int dt = 0; dt < 4; ++dt) {
                #pragma unroll
                for (int ks = 0; ks < 4; ++ks) {
                    const int gg = 8 * (q5 & 1) +
                        ((2 * ks + t5) ^ ((q5 >> 1) & 7));
                    short8 vf = *(const short8*)
                        &Vt[buf][64 * wk + 16 * dt + (q5 >> 1)][8 * gg];
                    oacc[dt] = __builtin_amdgcn_mfma_f32_32x32x16_bf16(vf, pf[ks].s, oacc[dt], 0, 0, 0);
                }
            }
            __builtin_amdgcn_s_setprio(0);
        }

        asm volatile("" ::: "memory");
        __builtin_amdgcn_s_barrier();
        if (s + 2 < 17) {
            const int s2 = s + 2;
            ISSUE((s2 < nsB) ? 128 * s2 : 128 * (s2 - nsB), s & 1);
        }
    }

    EPI(QBa);
}

extern "C" void kernel_launch(void* const* d_in, const int* in_sizes, int n_in,
                              void* d_out, int out_size, void* d_ws, size_t ws_size,
                              hipStream_t stream) {
    const float* q = (const float*)d_in[0];
    const float* k = (const float*)d_in[1];
    const float* v = (const float*)d_in[2];
    float* out = (float*)d_out;
    unsigned short* Kb  = (unsigned short*)d_ws;                 // 4 MB
    unsigned short* Vtb = Kb + (size_t)8 * SEQ * 128;            // 4 MB
    prep_k<<<dim3(2048), 256, 0, stream>>>(k, Kb);
    prep_v<<<dim3(256), 256, 0, stream>>>(v, Vtb);
    attn_fwd<<<dim3(256), 512, 0, stream>>>(q, Kb, Vtb, out);
}